// Round 16
// baseline (68.993 us; speedup 1.0000x reference)
//
#include <hip/hip_runtime.h>

// RegistrationLoss: sim = -mean(NCC_9x9x9(warped, fixed)), reg = bending energy of flow,
// total = sim + 0.01*reg. Inputs f32: warped[2,1,128,128,128], fixed same, flow[2,3,128,128,128].
// Output: 3 floats [total, sim, reg].
//
// Round-16 structure (R15 + VALU-issue reduction in wh):
//   Evidence (R15 warm replays): FETCH~0, WRITE-only, same 45us duration -> kernel is
//   issue/stall-bound with all inputs L3-resident. VALU issue ~20us of 45. This round
//   cuts issue count; structure (4-deep prefetch, wh->bend phases, grids) frozen.
//   wh inner step: pair-sum W-box (p=x.x+x.y; 4 DPP on p + 2 edge DPP; 7 adds vs 11),
//   v2f ext-vector products/ring (v_pk_mul/add), v_cvt_pk_bf16_f32 packing (1 instr).
//   ncc_d:  R11's version (D-box ring, 1-step prefetch, uint4+dword loads).
// bufB row layout (per (b,d,h), 320 unsigned = 1280 B):
//   [0,256): uint4{bf2(f0),bf2(f1),bf2(f2),bf2(f3)} per w-pair at 4*wp
//   [256,320): bf2(f4) dword per w-pair
// Lessons kept: no min-waves launch_bounds (R4/R12); no per-LANE conditional loads (R5);
// no block-type mixing (R7); no single-wave stream merge (R13); compile-time indices
// (rule #20). Tripwire: VGPR>128 or WRITE >> 41 MB => void.

#define DIM 128
#define V   4194304L      // 2*128^3
#define NVOL6 12582912L   // 6*128^3

typedef float v2f __attribute__((ext_vector_type(2)));

#define ZER2 make_float2(0.f, 0.f)

__device__ __forceinline__ float2 unpack_bf2(unsigned u) {
    return make_float2(__uint_as_float(u << 16), __uint_as_float(u & 0xffff0000u));
}

// Packed f32x2 -> bf16x2 (RNE), low16 = src0, high16 = src1 — matches unpack_bf2.
__device__ __forceinline__ unsigned cvtpk_bf2(v2f v) {
    unsigned r;
    asm("v_cvt_pk_bf16_f32 %0, %1, %2" : "=v"(r) : "v"(v.x), "v"(v.y));
    return r;
}

// DPP wave-wide lane shifts. wave_shr:1 (0x138): lane i <- lane i-1 (lane 0 -> 0).
// wave_shl:1 (0x130): lane i <- lane i+1 (lane 63 -> 0). bound_ctrl=true: zero-fill.
__device__ __forceinline__ float dpp_up1(float x) {
    return __int_as_float(__builtin_amdgcn_mov_dpp(__float_as_int(x), 0x138, 0xF, 0xF, true));
}
__device__ __forceinline__ float dpp_dn1(float x) {
    return __int_as_float(__builtin_amdgcn_mov_dpp(__float_as_int(x), 0x130, 0xF, 0xF, true));
}

__device__ __forceinline__ float wave_block_reduce_partial(float local, float* lds, int t, int nwaves) {
    #pragma unroll
    for (int off = 32; off > 0; off >>= 1) local += __shfl_down(local, off, 64);
    if ((t & 63) == 0) lds[t >> 6] = local;
    __syncthreads();
    float s = 0.f;
    if (t == 0) {
        for (int i = 0; i < nwaves; ++i) s += lds[i];
    }
    return s; // valid on t==0 only
}

// ---------------- bending: split load / compute for 2-stage pipeline ----------------
struct BendData {
    float4 a0, aD, aD2, aH, aH2, aDH;
    float2 s45;
    float  sD4, sH4;
    int    w0, d, h;
};

__device__ __forceinline__ BendData bend_load(const float* __restrict__ F, int tid) {
    BendData B;
    const long e = (long)tid << 2;                  // element base (multiple of 4)
    const int r = (int)(e & 2097151);
    B.d = r >> 14;
    B.h = (r >> 7) & 127;
    B.w0 = r & 127;                                 // 0,4,...,124

    const float* p = F + e;
    const int off4 = (B.w0 < 124) ? 4 : 0;
    const int oD  = (B.d < 127) ? 16384 : 0;
    const int oD2 = (B.d < 126) ? 32768 : 0;
    const int oH  = (B.h < 127) ? 128 : 0;
    const int oH2 = (B.h < 126) ? 256 : 0;

    B.a0  = *reinterpret_cast<const float4*>(p);
    B.s45 = *reinterpret_cast<const float2*>(p + off4);
    B.aD  = *reinterpret_cast<const float4*>(p + oD);
    B.sD4 = (p + oD)[off4];
    B.aD2 = *reinterpret_cast<const float4*>(p + oD2);
    B.aH  = *reinterpret_cast<const float4*>(p + oH);
    B.sH4 = (p + oH)[off4];
    B.aH2 = *reinterpret_cast<const float4*>(p + oH2);
    B.aDH = *reinterpret_cast<const float4*>(p + oD + oH);
    return B;
}

__device__ __forceinline__ float bend_compute(const BendData& B) {
    const float invS = 1.0f / 12386304.0f;   // 6*126*128*128  (i==j)
    const float invC = 1.0f / 12289536.0f;   // 6*127*126*128  (i!=j, both orderings)

    const float A0[6] = {B.a0.x, B.a0.y, B.a0.z, B.a0.w, B.s45.x, B.s45.y};
    const float AD[5] = {B.aD.x, B.aD.y, B.aD.z, B.aD.w, B.sD4};
    const float AH[5] = {B.aH.x, B.aH.y, B.aH.z, B.aH.w, B.sH4};
    const float AD2[4] = {B.aD2.x, B.aD2.y, B.aD2.z, B.aD2.w};
    const float AH2[4] = {B.aH2.x, B.aH2.y, B.aH2.z, B.aH2.w};
    const float ADH[4] = {B.aDH.x, B.aDH.y, B.aDH.z, B.aDH.w};

    const float mD2 = (B.d < 126) ? invS : 0.f;
    const float mH2 = (B.h < 126) ? invS : 0.f;
    const float cD  = (B.d < 126) ? 1.f : 0.f;
    const float cH  = (B.h < 126) ? 1.f : 0.f;
    const bool  vD  = B.d < 127, vH = B.h < 127;

    float local = 0.f;
    #pragma unroll
    for (int k = 0; k < 4; ++k) {
        const int wk = B.w0 + k;
        const float mW2 = (wk < 126) ? invS : 0.f;
        const float cW  = (wk < 126) ? 1.f : 0.f;
        const bool  vW  = wk < 127;

        const float xW = A0[k + 2] - 2.f * A0[k + 1] + A0[k];
        local += xW * xW * mW2;
        const float xD = AD2[k] - 2.f * AD[k] + A0[k];
        local += xD * xD * mD2;
        const float xH = AH2[k] - 2.f * AH[k] + A0[k];
        local += xH * xH * mH2;

        const float xDH = ADH[k] - AD[k] - AH[k] + A0[k];
        local += xDH * xDH * (((vD && vH) ? (cD + cH) : 0.f) * invC);
        const float xDW = AD[k + 1] - AD[k] - A0[k + 1] + A0[k];
        local += xDW * xDW * (((vD && vW) ? (cD + cW) : 0.f) * invC);
        const float xHW = AH[k + 1] - AH[k] - A0[k + 1] + A0[k];
        local += xHW * xHW * (((vH && vW) ? (cH + cW) : 0.f) * invC);
    }
    return local;
}

// ---------------- Kernel 1: wh (pair-sum W-box, 4-deep prefetch) then bending ----------------
__global__ __launch_bounds__(256) void wh_bend(const float* __restrict__ I,
                                               const float* __restrict__ J,
                                               const float* __restrict__ F,
                                               unsigned* __restrict__ bufB,
                                               float* __restrict__ regPartial) {
    // ================= phase 1: products + W-box + H-box -> bufB =================
    {
        const int lane = threadIdx.x & 63;
        const int wv   = threadIdx.x >> 6;
        const int wid  = (blockIdx.x << 2) + wv;   // [0, 4096)
        const int e = wid & 15;           // h-chunk of 8
        const int d = (wid >> 4) & 127;
        const int b = wid >> 11;
        const int h0 = e << 3;
        const int w0 = lane << 1;
        const float* baseI = I + (b * 128 + d) * 16384 + w0;
        const float* baseJ = J + (b * 128 + d) * 16384 + w0;

        v2f win[9][5];
        v2f hs[5];
        #pragma unroll
        for (int f = 0; f < 5; ++f) hs[f] = (v2f){0.f, 0.f};

        // 4-deep row prefetch: slots hold rows h0-4+k for the next 4 steps
        v2f pa[4], pb[4];
        #pragma unroll
        for (int k = 0; k < 4; ++k) {
            const int h = h0 - 4 + k;
            if ((unsigned)h < 128u) {      // wave-uniform guard
                pa[k] = *reinterpret_cast<const v2f*>(baseI + h * 128);
                pb[k] = *reinterpret_cast<const v2f*>(baseJ + h * 128);
            } else {
                pa[k] = (v2f){0.f, 0.f}; pb[k] = (v2f){0.f, 0.f};
            }
        }

        #pragma unroll
        for (int s = 0; s < 16; ++s) {
            const v2f ci = pa[s & 3], cj = pb[s & 3];   // row h0-4+s
            if (s < 12) {
                const int h = h0 + s;                    // row for step s+4
                if ((unsigned)h < 128u) {
                    pa[s & 3] = *reinterpret_cast<const v2f*>(baseI + h * 128);
                    pb[s & 3] = *reinterpret_cast<const v2f*>(baseJ + h * 128);
                } else {
                    pa[s & 3] = (v2f){0.f, 0.f}; pb[s & 3] = (v2f){0.f, 0.f};
                }
            }

            // 5 fields; per field: pair-sum W-box (8 DPP + 7 adds)
            #pragma unroll
            for (int f = 0; f < 5; ++f) {
                v2f x;
                if      (f == 0) x = ci;
                else if (f == 1) x = cj;
                else if (f == 2) x = ci * ci;    // v_pk_mul_f32
                else if (f == 3) x = cj * cj;
                else             x = ci * cj;

                const float p   = x.x + x.y;          // elements w, w+1
                const float pm1 = dpp_up1(p);         // w-2, w-1
                const float pm2 = dpp_up1(pm1);       // w-4, w-3
                const float pp1 = dpp_dn1(p);         // w+2, w+3
                const float pp2 = dpp_dn1(pp1);       // w+4, w+5
                const float u1y = dpp_up1(x.y);       // elem w-1
                const float u2y = dpp_up1(u1y);       // elem w-3
                const float d1x = dpp_dn1(x.x);       // elem w+2
                const float d2x = dpp_dn1(d1x);       // elem w+4

                const float q = pm1 + p + pp1;        // w-2..w+3
                v2f wb;
                wb.x = q + pm2 + d2x;                 // window w-4..w+4
                wb.y = q + u2y + pp2;                 // window w-3..w+5

                if (s >= 9) hs[f] -= win[s % 9][f];   // v_pk_add_f32
                hs[f] += wb;
                win[s % 9][f] = wb;
            }

            if (s >= 8) {
                const int h_out = h0 + s - 8;
                unsigned* row = bufB + ((b * 128 + d) * 128 + h_out) * 320;
                const uint4 pk = make_uint4(cvtpk_bf2(hs[0]), cvtpk_bf2(hs[1]),
                                            cvtpk_bf2(hs[2]), cvtpk_bf2(hs[3]));
                *reinterpret_cast<uint4*>(row + 4 * lane) = pk;
                row[256 + lane] = cvtpk_bf2(hs[4]);
            }
        }
    }

    // ================= phase 2: bending energy (2-stage pipelined) =================
    {
        float bendAcc = 0.f;
        BendData cur = bend_load(F, blockIdx.x * 256 + threadIdx.x);   // it = 0
        #pragma unroll
        for (int it = 0; it < 11; ++it) {
            BendData nxt = bend_load(F, (blockIdx.x + (it + 1) * 1024) * 256 + threadIdx.x);
            bendAcc += bend_compute(cur);
            cur = nxt;
        }
        bendAcc += bend_compute(cur);

        __shared__ float rl[4];
        const float s = wave_block_reduce_partial(bendAcc, rl, threadIdx.x, 4);
        if (threadIdx.x == 0) regPartial[blockIdx.x] = s;
    }
}

// ---------------- Kernel 2: D-box + NCC + block reduce (R11 version) ----------------
__global__ __launch_bounds__(256) void ncc_d(const unsigned* __restrict__ bufB,
                                             float* __restrict__ nccPartial) {
    const int t = threadIdx.x;
    const int wp = t & 63;             // w-pair index
    const int sg = t >> 6;             // 0..3 (wave-uniform)
    const int b = blockIdx.x >> 9;
    const int h = (blockIdx.x >> 2) & 127;
    const int g = blockIdx.x & 3;
    const int d0 = ((g << 2) + sg) << 3;   // owned d: d0..d0+7
    const float inv_n = 1.0f / 729.0f;

    unsigned win[9][5];
    float2 rs[5];
    #pragma unroll
    for (int f = 0; f < 5; ++f) rs[f] = ZER2;
    float local = 0.f;

    // prefetch step 0 (dd = d0-4)
    uint4 nx = make_uint4(0u, 0u, 0u, 0u);
    unsigned nx4 = 0u;
    {
        const int dd = d0 - 4;
        if ((unsigned)dd < 128u) {
            const unsigned* row = bufB + ((b * 128 + dd) * 128 + h) * 320;
            nx = *reinterpret_cast<const uint4*>(row + 4 * wp);
            nx4 = row[256 + wp];
        }
    }

    #pragma unroll
    for (int s = 0; s < 16; ++s) {
        const uint4 cx = nx;
        const unsigned cx4 = nx4;
        if (s < 15) {
            const int dd = d0 - 3 + s;
            if ((unsigned)dd < 128u) {
                const unsigned* row = bufB + ((b * 128 + dd) * 128 + h) * 320;
                nx = *reinterpret_cast<const uint4*>(row + 4 * wp);
                nx4 = row[256 + wp];
            } else {
                nx = make_uint4(0u, 0u, 0u, 0u); nx4 = 0u;
            }
        }

        const unsigned x[5] = {cx.x, cx.y, cx.z, cx.w, cx4};
        #pragma unroll
        for (int f = 0; f < 5; ++f) {
            if (s >= 9) {
                const float2 o = unpack_bf2(win[s % 9][f]);
                rs[f].x -= o.x; rs[f].y -= o.y;
            }
            const float2 nv = unpack_bf2(x[f]);
            rs[f].x += nv.x; rs[f].y += nv.y;
            win[s % 9][f] = x[f];
        }
        if (s >= 8) {
            const float uix = rs[0].x * inv_n, uiy = rs[0].y * inv_n;
            const float ujx = rs[1].x * inv_n, ujy = rs[1].y * inv_n;
            const float i2x = rs[2].x * inv_n - uix * uix;
            const float i2y = rs[2].y * inv_n - uiy * uiy;
            const float j2x = rs[3].x * inv_n - ujx * ujx;
            const float j2y = rs[3].y * inv_n - ujy * ujy;
            const float ijx = rs[4].x * inv_n - uix * ujx;
            const float ijy = rs[4].y * inv_n - uiy * ujy;
            local += ijx * ijx / (i2x * j2x + 1e-5f)
                   + ijy * ijy / (i2y * j2y + 1e-5f);
        }
    }

    __shared__ float lds[4];
    const float s = wave_block_reduce_partial(local, lds, t, 4);
    if (t == 0) nccPartial[blockIdx.x] = s;
}

// ---------------- Finalize ----------------
__global__ void finalize(const float* __restrict__ nccPartial, const float* __restrict__ regPartial,
                         float* __restrict__ out) {
    __shared__ float sdata[256];
    const int t = threadIdx.x;
    float a = 0.f;
    for (int i = t; i < 1024; i += 256) a += nccPartial[i];
    sdata[t] = a; __syncthreads();
    for (int s = 128; s > 0; s >>= 1) { if (t < s) sdata[t] += sdata[t + s]; __syncthreads(); }
    const float nccSum = sdata[0];
    __syncthreads();
    float bsum = 0.f;
    for (int i = t; i < 1024; i += 256) bsum += regPartial[i];
    sdata[t] = bsum; __syncthreads();
    for (int s = 128; s > 0; s >>= 1) { if (t < s) sdata[t] += sdata[t + s]; __syncthreads(); }
    if (t == 0) {
        const float reg = sdata[0];
        const float sim = -nccSum / (float)V;
        out[0] = sim + 0.01f * reg;
        out[1] = sim;
        out[2] = reg;
    }
}

extern "C" void kernel_launch(void* const* d_in, const int* in_sizes, int n_in,
                              void* d_out, int out_size, void* d_ws, size_t ws_size,
                              hipStream_t stream) {
    const float* warped = (const float*)d_in[0];
    const float* fixedv = (const float*)d_in[1];
    const float* flow   = (const float*)d_in[2];
    float* out = (float*)d_out;
    float* ws  = (float*)d_ws;

    // ws layout (floats): [0,1024) nccPartial | [1024,2048) regPartial | pad |
    //                     [16384, ...) bufB packed bf16 (2*128^3*5*2B ~= 42 MB)
    float* nccPartial = ws;
    float* regPartial = ws + 1024;
    unsigned* bufB = (unsigned*)(ws + 16384);

    // 1024 identical blocks = 4096 wh-waves; bending tail-fill in-phase
    wh_bend<<<dim3(1024), dim3(256), 0, stream>>>(warped, fixedv, flow, bufB, regPartial);
    // 1024 blocks = (b, h, seg-group); 256 threads = w-pair x 4 d-segments
    ncc_d<<<dim3(1024), dim3(256), 0, stream>>>(bufB, nccPartial);
    finalize<<<dim3(1), dim3(256), 0, stream>>>(nccPartial, regPartial, out);
}

// Round 17
// 52.257 us; speedup vs baseline: 1.3203x; 1.3203x over previous
//
#include <hip/hip_runtime.h>

// RegistrationLoss: sim = -mean(NCC_9x9x9(warped, fixed)), reg = bending energy of flow,
// total = sim + 0.01*reg. Inputs f32: warped[2,1,128,128,128], fixed same, flow[2,3,128,128,128].
// Output: 3 floats [total, sim, reg].
//
// Round-17: verbatim revert to R15 (best, 52.3us). R16's VALU-reduction bundle raised
// VGPR to 156 (>128 cliff; 40 DPP/step vs 16 — pair-sum shifts per-FIELD lose to
// shifting the shared inputs; inline-asm cvt_pk pins operands) -> occupancy halved.
// R15 operating point (verified over R9-R16):
//   - all inputs L3-resident in steady state (warm FETCH~0) -> not HBM-BW-bound
//   - VGPR 108 -> 4 waves/SIMD (quantization: halves at 64/128/256). <=64 unreachable
//     (R12 spill storm), >128 halves occupancy (R13/R16). This band is forced.
//   - 4-deep prefetch (R15's +5us win) saturates the vmcnt pipeline at this occupancy.
//   - LDS round-trip and DPP W-window are equivalent (R9 vs R11) — stall is structural.
//   wh_bend: wh phase (DPP W-views, W-box, H-box f32 ring, bufB packed bf16 42 MB,
//            4-deep row prefetch) then bending phase (2-stage pipelined float4 iters).
//   ncc_d:  D-box ring, 1-step prefetch, uint4+dword loads, NCC + block reduce.
// bufB row layout (per (b,d,h), 320 unsigned = 1280 B):
//   [0,256): uint4{bf2(f0),bf2(f1),bf2(f2),bf2(f3)} per w-pair at 4*wp
//   [256,320): bf2(f4) dword per w-pair
// Lessons: no min-waves launch_bounds (R4/R12); no per-LANE conditional loads (R5);
// no block-type mixing (R7); no single-wave stream merge (R13); no per-field DPP (R16);
// compile-time indices (rule #20).

#define DIM 128
#define V   4194304L      // 2*128^3
#define NVOL6 12582912L   // 6*128^3

#define ZER2 make_float2(0.f, 0.f)

__device__ __forceinline__ unsigned pack_bf2(float2 v) {
    unsigned ax = __float_as_uint(v.x), ay = __float_as_uint(v.y);
    ax = ax + 0x7fffu + ((ax >> 16) & 1u);      // round-to-nearest-even
    ay = ay + 0x7fffu + ((ay >> 16) & 1u);
    return (ax >> 16) | (ay & 0xffff0000u);
}
__device__ __forceinline__ float2 unpack_bf2(unsigned u) {
    return make_float2(__uint_as_float(u << 16), __uint_as_float(u & 0xffff0000u));
}

// DPP wave-wide lane shifts. wave_shr:1 (0x138): lane i <- lane i-1 (lane 0 -> 0).
// wave_shl:1 (0x130): lane i <- lane i+1 (lane 63 -> 0). bound_ctrl=true: zero-fill.
__device__ __forceinline__ float dpp_up1(float x) {
    return __int_as_float(__builtin_amdgcn_mov_dpp(__float_as_int(x), 0x138, 0xF, 0xF, true));
}
__device__ __forceinline__ float dpp_dn1(float x) {
    return __int_as_float(__builtin_amdgcn_mov_dpp(__float_as_int(x), 0x130, 0xF, 0xF, true));
}
__device__ __forceinline__ float2 dpp_up1_f2(float2 v) {
    return make_float2(dpp_up1(v.x), dpp_up1(v.y));
}
__device__ __forceinline__ float2 dpp_dn1_f2(float2 v) {
    return make_float2(dpp_dn1(v.x), dpp_dn1(v.y));
}

__device__ __forceinline__ float wave_block_reduce_partial(float local, float* lds, int t, int nwaves) {
    #pragma unroll
    for (int off = 32; off > 0; off >>= 1) local += __shfl_down(local, off, 64);
    if ((t & 63) == 0) lds[t >> 6] = local;
    __syncthreads();
    float s = 0.f;
    if (t == 0) {
        for (int i = 0; i < nwaves; ++i) s += lds[i];
    }
    return s; // valid on t==0 only
}

// ---------------- bending: split load / compute for 2-stage pipeline ----------------
struct BendData {
    float4 a0, aD, aD2, aH, aH2, aDH;
    float2 s45;
    float  sD4, sH4;
    int    w0, d, h;
};

__device__ __forceinline__ BendData bend_load(const float* __restrict__ F, int tid) {
    BendData B;
    const long e = (long)tid << 2;                  // element base (multiple of 4)
    const int r = (int)(e & 2097151);
    B.d = r >> 14;
    B.h = (r >> 7) & 127;
    B.w0 = r & 127;                                 // 0,4,...,124

    const float* p = F + e;
    const int off4 = (B.w0 < 124) ? 4 : 0;
    const int oD  = (B.d < 127) ? 16384 : 0;
    const int oD2 = (B.d < 126) ? 32768 : 0;
    const int oH  = (B.h < 127) ? 128 : 0;
    const int oH2 = (B.h < 126) ? 256 : 0;

    B.a0  = *reinterpret_cast<const float4*>(p);
    B.s45 = *reinterpret_cast<const float2*>(p + off4);
    B.aD  = *reinterpret_cast<const float4*>(p + oD);
    B.sD4 = (p + oD)[off4];
    B.aD2 = *reinterpret_cast<const float4*>(p + oD2);
    B.aH  = *reinterpret_cast<const float4*>(p + oH);
    B.sH4 = (p + oH)[off4];
    B.aH2 = *reinterpret_cast<const float4*>(p + oH2);
    B.aDH = *reinterpret_cast<const float4*>(p + oD + oH);
    return B;
}

__device__ __forceinline__ float bend_compute(const BendData& B) {
    const float invS = 1.0f / 12386304.0f;   // 6*126*128*128  (i==j)
    const float invC = 1.0f / 12289536.0f;   // 6*127*126*128  (i!=j, both orderings)

    const float A0[6] = {B.a0.x, B.a0.y, B.a0.z, B.a0.w, B.s45.x, B.s45.y};
    const float AD[5] = {B.aD.x, B.aD.y, B.aD.z, B.aD.w, B.sD4};
    const float AH[5] = {B.aH.x, B.aH.y, B.aH.z, B.aH.w, B.sH4};
    const float AD2[4] = {B.aD2.x, B.aD2.y, B.aD2.z, B.aD2.w};
    const float AH2[4] = {B.aH2.x, B.aH2.y, B.aH2.z, B.aH2.w};
    const float ADH[4] = {B.aDH.x, B.aDH.y, B.aDH.z, B.aDH.w};

    const float mD2 = (B.d < 126) ? invS : 0.f;
    const float mH2 = (B.h < 126) ? invS : 0.f;
    const float cD  = (B.d < 126) ? 1.f : 0.f;
    const float cH  = (B.h < 126) ? 1.f : 0.f;
    const bool  vD  = B.d < 127, vH = B.h < 127;

    float local = 0.f;
    #pragma unroll
    for (int k = 0; k < 4; ++k) {
        const int wk = B.w0 + k;
        const float mW2 = (wk < 126) ? invS : 0.f;
        const float cW  = (wk < 126) ? 1.f : 0.f;
        const bool  vW  = wk < 127;

        const float xW = A0[k + 2] - 2.f * A0[k + 1] + A0[k];
        local += xW * xW * mW2;
        const float xD = AD2[k] - 2.f * AD[k] + A0[k];
        local += xD * xD * mD2;
        const float xH = AH2[k] - 2.f * AH[k] + A0[k];
        local += xH * xH * mH2;

        const float xDH = ADH[k] - AD[k] - AH[k] + A0[k];
        local += xDH * xDH * (((vD && vH) ? (cD + cH) : 0.f) * invC);
        const float xDW = AD[k + 1] - AD[k] - A0[k + 1] + A0[k];
        local += xDW * xDW * (((vD && vW) ? (cD + cW) : 0.f) * invC);
        const float xHW = AH[k + 1] - AH[k] - A0[k + 1] + A0[k];
        local += xHW * xHW * (((vH && vW) ? (cH + cW) : 0.f) * invC);
    }
    return local;
}

// ---------------- Kernel 1: wh (4-deep prefetch) then bending (2-stage pipeline) ----------------
__global__ __launch_bounds__(256) void wh_bend(const float* __restrict__ I,
                                               const float* __restrict__ J,
                                               const float* __restrict__ F,
                                               unsigned* __restrict__ bufB,
                                               float* __restrict__ regPartial) {
    // ================= phase 1: products + W-box + H-box -> bufB =================
    {
        const int lane = threadIdx.x & 63;
        const int wv   = threadIdx.x >> 6;
        const int wid  = (blockIdx.x << 2) + wv;   // [0, 4096)
        const int e = wid & 15;           // h-chunk of 8
        const int d = (wid >> 4) & 127;
        const int b = wid >> 11;
        const int h0 = e << 3;
        const int w0 = lane << 1;
        const float* baseI = I + (b * 128 + d) * 16384 + w0;
        const float* baseJ = J + (b * 128 + d) * 16384 + w0;

        float2 win[9][5];
        float2 hs[5];
        #pragma unroll
        for (int f = 0; f < 5; ++f) hs[f] = ZER2;

        // 4-deep row prefetch: slots hold rows h0-4+k for the next 4 steps
        float2 pa[4], pb[4];
        #pragma unroll
        for (int k = 0; k < 4; ++k) {
            const int h = h0 - 4 + k;
            if ((unsigned)h < 128u) {      // wave-uniform guard
                pa[k] = *reinterpret_cast<const float2*>(baseI + h * 128);
                pb[k] = *reinterpret_cast<const float2*>(baseJ + h * 128);
            } else {
                pa[k] = ZER2; pb[k] = ZER2;
            }
        }

        #pragma unroll
        for (int s = 0; s < 16; ++s) {
            const float2 ci = pa[s & 3], cj = pb[s & 3];   // row h0-4+s
            if (s < 12) {
                const int h = h0 + s;                       // row for step s+4
                if ((unsigned)h < 128u) {
                    pa[s & 3] = *reinterpret_cast<const float2*>(baseI + h * 128);
                    pb[s & 3] = *reinterpret_cast<const float2*>(baseJ + h * 128);
                } else {
                    pa[s & 3] = ZER2; pb[s & 3] = ZER2;
                }
            }

            // 5 shifted W-views via DPP lane shifts (element offsets -4,-2,0,+2,+4)
            float2 iv[5], jv[5];
            iv[2] = ci;                jv[2] = cj;
            iv[1] = dpp_up1_f2(ci);    jv[1] = dpp_up1_f2(cj);
            iv[0] = dpp_up1_f2(iv[1]); jv[0] = dpp_up1_f2(jv[1]);
            iv[3] = dpp_dn1_f2(ci);    jv[3] = dpp_dn1_f2(cj);
            iv[4] = dpp_dn1_f2(iv[3]); jv[4] = dpp_dn1_f2(jv[3]);

            float2 v[5][5];
            #pragma unroll
            for (int o = 0; o < 5; ++o) {
                v[0][o] = iv[o];
                v[1][o] = jv[o];
                v[2][o] = make_float2(iv[o].x * iv[o].x, iv[o].y * iv[o].y);
                v[3][o] = make_float2(jv[o].x * jv[o].x, jv[o].y * jv[o].y);
                v[4][o] = make_float2(iv[o].x * jv[o].x, iv[o].y * jv[o].y);
            }

            #pragma unroll
            for (int f = 0; f < 5; ++f) {
                const float core = v[f][1].x + v[f][1].y + v[f][2].x + v[f][2].y
                                 + v[f][3].x + v[f][3].y;
                float2 wb;
                wb.x = core + v[f][0].x + v[f][0].y + v[f][4].x;   // window w-4..w+4
                wb.y = core + v[f][0].y + v[f][4].x + v[f][4].y;   // window w-3..w+5
                if (s >= 9) { hs[f].x -= win[s % 9][f].x; hs[f].y -= win[s % 9][f].y; }
                hs[f].x += wb.x; hs[f].y += wb.y;
                win[s % 9][f] = wb;
            }

            if (s >= 8) {
                const int h_out = h0 + s - 8;
                unsigned* row = bufB + ((b * 128 + d) * 128 + h_out) * 320;
                const uint4 pk = make_uint4(pack_bf2(hs[0]), pack_bf2(hs[1]),
                                            pack_bf2(hs[2]), pack_bf2(hs[3]));
                *reinterpret_cast<uint4*>(row + 4 * lane) = pk;
                row[256 + lane] = pack_bf2(hs[4]);
            }
        }
    }

    // ================= phase 2: bending energy (2-stage pipelined) =================
    {
        float bendAcc = 0.f;
        BendData cur = bend_load(F, blockIdx.x * 256 + threadIdx.x);   // it = 0
        #pragma unroll
        for (int it = 0; it < 11; ++it) {
            BendData nxt = bend_load(F, (blockIdx.x + (it + 1) * 1024) * 256 + threadIdx.x);
            bendAcc += bend_compute(cur);
            cur = nxt;
        }
        bendAcc += bend_compute(cur);

        __shared__ float rl[4];
        const float s = wave_block_reduce_partial(bendAcc, rl, threadIdx.x, 4);
        if (threadIdx.x == 0) regPartial[blockIdx.x] = s;
    }
}

// ---------------- Kernel 2: D-box + NCC + block reduce (R11 version) ----------------
__global__ __launch_bounds__(256) void ncc_d(const unsigned* __restrict__ bufB,
                                             float* __restrict__ nccPartial) {
    const int t = threadIdx.x;
    const int wp = t & 63;             // w-pair index
    const int sg = t >> 6;             // 0..3 (wave-uniform)
    const int b = blockIdx.x >> 9;
    const int h = (blockIdx.x >> 2) & 127;
    const int g = blockIdx.x & 3;
    const int d0 = ((g << 2) + sg) << 3;   // owned d: d0..d0+7
    const float inv_n = 1.0f / 729.0f;

    unsigned win[9][5];
    float2 rs[5];
    #pragma unroll
    for (int f = 0; f < 5; ++f) rs[f] = ZER2;
    float local = 0.f;

    // prefetch step 0 (dd = d0-4)
    uint4 nx = make_uint4(0u, 0u, 0u, 0u);
    unsigned nx4 = 0u;
    {
        const int dd = d0 - 4;
        if ((unsigned)dd < 128u) {
            const unsigned* row = bufB + ((b * 128 + dd) * 128 + h) * 320;
            nx = *reinterpret_cast<const uint4*>(row + 4 * wp);
            nx4 = row[256 + wp];
        }
    }

    #pragma unroll
    for (int s = 0; s < 16; ++s) {
        const uint4 cx = nx;
        const unsigned cx4 = nx4;
        if (s < 15) {
            const int dd = d0 - 3 + s;
            if ((unsigned)dd < 128u) {
                const unsigned* row = bufB + ((b * 128 + dd) * 128 + h) * 320;
                nx = *reinterpret_cast<const uint4*>(row + 4 * wp);
                nx4 = row[256 + wp];
            } else {
                nx = make_uint4(0u, 0u, 0u, 0u); nx4 = 0u;
            }
        }

        const unsigned x[5] = {cx.x, cx.y, cx.z, cx.w, cx4};
        #pragma unroll
        for (int f = 0; f < 5; ++f) {
            if (s >= 9) {
                const float2 o = unpack_bf2(win[s % 9][f]);
                rs[f].x -= o.x; rs[f].y -= o.y;
            }
            const float2 nv = unpack_bf2(x[f]);
            rs[f].x += nv.x; rs[f].y += nv.y;
            win[s % 9][f] = x[f];
        }
        if (s >= 8) {
            const float uix = rs[0].x * inv_n, uiy = rs[0].y * inv_n;
            const float ujx = rs[1].x * inv_n, ujy = rs[1].y * inv_n;
            const float i2x = rs[2].x * inv_n - uix * uix;
            const float i2y = rs[2].y * inv_n - uiy * uiy;
            const float j2x = rs[3].x * inv_n - ujx * ujx;
            const float j2y = rs[3].y * inv_n - ujy * ujy;
            const float ijx = rs[4].x * inv_n - uix * ujx;
            const float ijy = rs[4].y * inv_n - uiy * ujy;
            local += ijx * ijx / (i2x * j2x + 1e-5f)
                   + ijy * ijy / (i2y * j2y + 1e-5f);
        }
    }

    __shared__ float lds[4];
    const float s = wave_block_reduce_partial(local, lds, t, 4);
    if (t == 0) nccPartial[blockIdx.x] = s;
}

// ---------------- Finalize ----------------
__global__ void finalize(const float* __restrict__ nccPartial, const float* __restrict__ regPartial,
                         float* __restrict__ out) {
    __shared__ float sdata[256];
    const int t = threadIdx.x;
    float a = 0.f;
    for (int i = t; i < 1024; i += 256) a += nccPartial[i];
    sdata[t] = a; __syncthreads();
    for (int s = 128; s > 0; s >>= 1) { if (t < s) sdata[t] += sdata[t + s]; __syncthreads(); }
    const float nccSum = sdata[0];
    __syncthreads();
    float bsum = 0.f;
    for (int i = t; i < 1024; i += 256) bsum += regPartial[i];
    sdata[t] = bsum; __syncthreads();
    for (int s = 128; s > 0; s >>= 1) { if (t < s) sdata[t] += sdata[t + s]; __syncthreads(); }
    if (t == 0) {
        const float reg = sdata[0];
        const float sim = -nccSum / (float)V;
        out[0] = sim + 0.01f * reg;
        out[1] = sim;
        out[2] = reg;
    }
}

extern "C" void kernel_launch(void* const* d_in, const int* in_sizes, int n_in,
                              void* d_out, int out_size, void* d_ws, size_t ws_size,
                              hipStream_t stream) {
    const float* warped = (const float*)d_in[0];
    const float* fixedv = (const float*)d_in[1];
    const float* flow   = (const float*)d_in[2];
    float* out = (float*)d_out;
    float* ws  = (float*)d_ws;

    // ws layout (floats): [0,1024) nccPartial | [1024,2048) regPartial | pad |
    //                     [16384, ...) bufB packed bf16 (2*128^3*5*2B ~= 42 MB)
    float* nccPartial = ws;
    float* regPartial = ws + 1024;
    unsigned* bufB = (unsigned*)(ws + 16384);

    // 1024 identical blocks = 4096 wh-waves; bending tail-fill in-phase
    wh_bend<<<dim3(1024), dim3(256), 0, stream>>>(warped, fixedv, flow, bufB, regPartial);
    // 1024 blocks = (b, h, seg-group); 256 threads = w-pair x 4 d-segments
    ncc_d<<<dim3(1024), dim3(256), 0, stream>>>(bufB, nccPartial);
    finalize<<<dim3(1), dim3(256), 0, stream>>>(nccPartial, regPartial, out);
}